// Round 11
// baseline (147.808 us; speedup 1.0000x reference)
//
#include <hip/hip_runtime.h>
#include <math.h>
#include <stdint.h>

typedef __attribute__((ext_vector_type(8))) short short8;
typedef __attribute__((ext_vector_type(4))) float f32x4;

#define B_  16
#define C_  256
#define HW_ 4096
#define KK_ 49
#define CR_ 64

__device__ __forceinline__ ushort f2bf(float f) {
    union { float f; uint32_t u; } v; v.f = f;
    uint32_t r = (v.u + 0x7FFFu + ((v.u >> 16) & 1u)) >> 16;
    return (ushort)r;
}

#define GLDS4(gp, lp) __builtin_amdgcn_global_load_lds(\
    (const __attribute__((address_space(1))) uint32_t*)(gp), \
    (__attribute__((address_space(3))) uint32_t*)(lp), 4, 0, 0)

// ---------------- K1: global average pool ----------------
__global__ __launch_bounds__(256) void pool_kernel(const float* __restrict__ x,
                                                   float* __restrict__ pooled) {
    int bc = blockIdx.x;
    const float4* p4 = (const float4*)(x + (size_t)bc * HW_);
    float s = 0.f;
    for (int i = threadIdx.x; i < HW_ / 4; i += 256) {
        float4 v = p4[i];
        s += (v.x + v.y) + (v.z + v.w);
    }
#pragma unroll
    for (int off = 32; off > 0; off >>= 1) s += __shfl_down(s, off);
    __shared__ float red[4];
    if ((threadIdx.x & 63) == 0) red[threadIdx.x >> 6] = s;
    __syncthreads();
    if (threadIdx.x == 0)
        pooled[bc] = (red[0] + red[1] + red[2] + red[3]) * (1.f / HW_);
}

// ---------------- K2: fused mlp + genw ----------------
__global__ __launch_bounds__(256) void mlpgenw_kernel(const float* __restrict__ pooled,
                                                      const float* __restrict__ w1,
                                                      const float* __restrict__ b1,
                                                      const float* __restrict__ w2,
                                                      const float* __restrict__ b2,
                                                      const float* __restrict__ dwt,
                                                      float* __restrict__ fused) {
    __shared__ float ps[B_ * C_];
    __shared__ float hs[B_ * CR_];
    const int tid = threadIdx.x;
    for (int i = tid; i < B_ * C_; i += 256) ps[i] = pooled[i];
    __syncthreads();
    for (int v = tid; v < B_ * CR_; v += 256) {
        int b = v >> 6, r = v & 63;
        float acc = b1[r];
        const float* wr = w1 + (size_t)r * C_;
        const float* pb = ps + b * C_;
        for (int c = 0; c < C_; c += 4) {
            float4 wv = *(const float4*)(wr + c);
            acc += pb[c] * wv.x + pb[c + 1] * wv.y + pb[c + 2] * wv.z + pb[c + 3] * wv.w;
        }
        hs[v] = 0.5f * acc * (1.f + erff(acc * 0.70710678118654752f));
    }
    __syncthreads();

    int m = blockIdx.x * 256 + tid;   // < 12544
    float wrow[CR_];
    const float4* w4 = (const float4*)(w2 + (size_t)m * CR_);
#pragma unroll
    for (int i = 0; i < CR_ / 4; i++) {
        float4 v = w4[i];
        wrow[4 * i] = v.x; wrow[4 * i + 1] = v.y;
        wrow[4 * i + 2] = v.z; wrow[4 * i + 3] = v.w;
    }
    float base = b2[m] + dwt[m];
    for (int b = 0; b < B_; b++) {
        float acc = base;
        const float* hb = hs + b * CR_;
#pragma unroll
        for (int r = 0; r < CR_; r++) acc += hb[r] * wrow[r];
        fused[(size_t)b * (C_ * KK_) + m] = acc;
    }
}

// ---------------- K3: pack pw fp32 [o][c] -> Pa bf16 [c/32][o/16][(c&31)/8][o&15][c&7] ----
// A-fragment-direct layout: lane (o=lane&15, kq=lane>>4) reads b128 at
// (((kb*16+ob)*4+kq)*16 + o)*8 ushorts  -> 512B contiguous per wave-fragment.
__global__ __launch_bounds__(256) void prep_kernel(const float* __restrict__ pw,
                                                   ushort* __restrict__ Pa) {
    int idx = blockIdx.x * 256 + threadIdx.x;   // 65536
    int o = idx >> 8, c = idx & 255;
    size_t e = (size_t)((((c >> 5) * 16 + (o >> 4)) * 4 + ((c >> 3) & 3)) * 128)
             + (o & 15) * 8 + (c & 7);
    Pa[e] = f2bf(pw[idx]);
}

// ---------------- K4: fused depthwise + pointwise ----------------
// Block = (band, b): output Y[b][0..255][band*256 .. +255]  (4 image rows).
// 16 iters x 16 channels: async x-stage (dbuf, wave-private) -> dw fp32 ->
// pack U bf16 into Us[k of 32] -> every 2nd iter: MFMA k=32 accumulate.
__global__ __launch_bounds__(512, 2) void dwpw_kernel(const float* __restrict__ x,
                                                      const float* __restrict__ fused,
                                                      const ushort* __restrict__ Pa,
                                                      float* __restrict__ Y) {
    __shared__ __align__(16) float  xs[2][16][10][72];   // 92160 B
    __shared__ __align__(16) ushort Us[16][16][40];      // 20480 B (px-stride 40: 16B-aligned b128)

    const int band = blockIdx.x;         // 0..15
    const int b    = blockIdx.y;
    const int tid  = threadIdx.x;        // 0..511
    const int wid  = tid >> 6;           // wave 0..7
    const int lane = tid & 63;
    const int r0   = band * 4;           // first output image row
    const int ow   = wid >> 2;           // o-half 0..1
    const int pq   = wid & 3;            // px-quarter 0..3
    const int cg   = lane & 15;          // 4-col group
    const int rg   = lane >> 4;          // output row within band 0..3
    const int oi   = lane & 15;
    const int kq   = lane >> 4;

    // ---- zero both xs buffers once (edges + OOB rows stay 0 forever) ----
    {
        float* xf = &xs[0][0][0][0];
        for (int i = tid; i < 2 * 16 * 10 * 72; i += 512) xf[i] = 0.f;
    }
    __syncthreads();

    // stage channels for iteration IT into xs[IT&1]; wave-private slots {wid, wid+8}
#define STAGE(IT)                                                                  \
    {                                                                              \
        _Pragma("unroll")                                                          \
        for (int q = 0; q < 2; q++) {                                              \
            const int slot = wid + 8 * q;                                          \
            const int ch   = (IT) * 16 + slot;                                     \
            const float* xp = x + (((size_t)b * C_ + ch) << 12);                   \
            _Pragma("unroll")                                                      \
            for (int row = 0; row < 10; row++) {                                   \
                int gr = r0 + row - 3;                                             \
                if ((unsigned)gr < 64u)                                            \
                    GLDS4(xp + (gr << 6) + lane, &xs[(IT) & 1][slot][row][4]);     \
            }                                                                      \
        }                                                                          \
    }

    f32x4 acc[8][4];
#pragma unroll
    for (int i = 0; i < 8; i++)
#pragma unroll
        for (int j = 0; j < 4; j++) acc[i][j] = (f32x4){0.f, 0.f, 0.f, 0.f};

    STAGE(0)

    for (int it = 0; it < 16; it++) {
        asm volatile("s_waitcnt vmcnt(0)" ::: "memory");   // xs[it&1] landed (wave-local)
        const int buf = it & 1;
        const bool mf = (it & 1) != 0;

        // A fragments for this k-block (issued early, consumed after barrier)
        short8 afrag[8];
        if (mf) {
            const int kb = it >> 1;
#pragma unroll
            for (int j = 0; j < 8; j++) {
                const int ob = ow * 8 + j;
                afrag[j] = *(const short8*)(Pa
                    + (size_t)(((kb * 16 + ob) * 4 + kq) * 128) + oi * 8);
            }
        }
        if (it < 15) STAGE(it + 1)

        // ---- dw: 2 channels per wave, 4 px each lane ----
#pragma unroll
        for (int s = 0; s < 2; s++) {
            const int slot = wid + 8 * s;
            const int ch   = it * 16 + slot;
            const float* fp = fused + ((size_t)b * C_ + ch) * KK_;
            float v = (lane < KK_) ? fp[lane] : 0.f;
            int vi = __float_as_int(v);
            float wk[49];
#pragma unroll
            for (int t = 0; t < 49; t++) {
                wk[t] = __int_as_float(__builtin_amdgcn_readlane(vi, t));
                asm volatile("" : "+s"(wk[t]));
            }
            float a4[4] = {0.f, 0.f, 0.f, 0.f};
            const float* xb = &xs[buf][slot][0][cg * 4];
#pragma unroll
            for (int ki = 0; ki < 7; ki++) {
                float xr[12];
                const float* rp = xb + (rg + ki) * 72;
                *(float4*)&xr[0] = *(const float4*)rp;
                *(float4*)&xr[4] = *(const float4*)(rp + 4);
                *(float4*)&xr[8] = *(const float4*)(rp + 8);
#pragma unroll
                for (int kj = 0; kj < 7; kj++)
#pragma unroll
                    for (int co = 0; co < 4; co++)
                        a4[co] = fmaf(xr[co + 1 + kj], wk[ki * 7 + kj], a4[co]);
            }
            const int k = buf * 16 + slot;   // k within 32-block
#pragma unroll
            for (int co = 0; co < 4; co++) {
                int px = rg * 64 + cg * 4 + co;
                Us[px >> 4][px & 15][k] = f2bf(a4[co]);
            }
        }

        if (mf) {
            __syncthreads();   // all 32 k-slices of Us visible
            short8 bfrag[4];
#pragma unroll
            for (int j = 0; j < 4; j++)
                bfrag[j] = *(const short8*)&Us[pq * 4 + j][oi][kq * 8];
#pragma unroll
            for (int i = 0; i < 8; i++)
#pragma unroll
                for (int j = 0; j < 4; j++)
                    acc[i][j] = __builtin_amdgcn_mfma_f32_16x16x32_bf16(
                        afrag[i], bfrag[j], acc[i][j], 0, 0, 0);
            __syncthreads();   // Us consumed before next packs
        }
    }

    // ---- epilogue: D row = o ((lane>>4)*4+r), col = px (lane&15) ----
    float* yb = Y + ((size_t)b << 20) + band * 256;
#pragma unroll
    for (int i = 0; i < 8; i++) {
#pragma unroll
        for (int j = 0; j < 4; j++) {
            const int p = pq * 64 + j * 16 + oi;
#pragma unroll
            for (int r = 0; r < 4; r++) {
                const int o = ow * 128 + i * 16 + kq * 4 + r;
                yb[(size_t)o * HW_ + p] = acc[i][j][r];
            }
        }
    }
#undef STAGE
}

extern "C" void kernel_launch(void* const* d_in, const int* in_sizes, int n_in,
                              void* d_out, int out_size, void* d_ws, size_t ws_size,
                              hipStream_t stream) {
    const float* x  = (const float*)d_in[0];
    const float* dw = (const float*)d_in[1];
    const float* pw = (const float*)d_in[2];
    const float* w1 = (const float*)d_in[3];
    const float* b1 = (const float*)d_in[4];
    const float* w2 = (const float*)d_in[5];
    const float* b2 = (const float*)d_in[6];
    float* out = (float*)d_out;

    char* ws = (char*)d_ws;
    float*  pooled = (float*)(ws);                    // 16384 B
    float*  fused  = (float*)(ws + 16384);            // 802816 B
    ushort* Pa     = (ushort*)(ws + 819200);          // 131072 B

    hipLaunchKernelGGL(pool_kernel,    dim3(B_ * C_), dim3(256), 0, stream, x, pooled);
    hipLaunchKernelGGL(mlpgenw_kernel, dim3(49), dim3(256), 0, stream,
                       pooled, w1, b1, w2, b2, dw, fused);
    hipLaunchKernelGGL(prep_kernel,    dim3(256), dim3(256), 0, stream, pw, Pa);
    hipLaunchKernelGGL(dwpw_kernel,    dim3(16, B_), dim3(512), 0, stream,
                       x, fused, Pa, out);
}

// Round 13
// 123.363 us; speedup vs baseline: 1.1981x; 1.1981x over previous
//
#include <hip/hip_runtime.h>
#include <math.h>
#include <stdint.h>

typedef __attribute__((ext_vector_type(8))) short short8;
typedef __attribute__((ext_vector_type(4))) float f32x4;

#define B_  16
#define C_  256
#define HW_ 4096
#define KK_ 49
#define CR_ 64

__device__ __forceinline__ ushort f2bf(float f) {
    union { float f; uint32_t u; } v; v.f = f;
    uint32_t r = (v.u + 0x7FFFu + ((v.u >> 16) & 1u)) >> 16;
    return (ushort)r;
}

#define GLDS16(gp, lp) __builtin_amdgcn_global_load_lds(\
    (const __attribute__((address_space(1))) uint32_t*)(gp), \
    (__attribute__((address_space(3))) uint32_t*)(lp), 16, 0, 0)

// ---------------- K1: global average pool ----------------
__global__ __launch_bounds__(256) void pool_kernel(const float* __restrict__ x,
                                                   float* __restrict__ pooled) {
    int bc = blockIdx.x;
    const float4* p4 = (const float4*)(x + (size_t)bc * HW_);
    float s = 0.f;
    for (int i = threadIdx.x; i < HW_ / 4; i += 256) {
        float4 v = p4[i];
        s += (v.x + v.y) + (v.z + v.w);
    }
#pragma unroll
    for (int off = 32; off > 0; off >>= 1) s += __shfl_down(s, off);
    __shared__ float red[4];
    if ((threadIdx.x & 63) == 0) red[threadIdx.x >> 6] = s;
    __syncthreads();
    if (threadIdx.x == 0)
        pooled[bc] = (red[0] + red[1] + red[2] + red[3]) * (1.f / HW_);
}

// ---------------- K2: fused mlp + genw ----------------
__global__ __launch_bounds__(256) void mlpgenw_kernel(const float* __restrict__ pooled,
                                                      const float* __restrict__ w1,
                                                      const float* __restrict__ b1,
                                                      const float* __restrict__ w2,
                                                      const float* __restrict__ b2,
                                                      const float* __restrict__ dwt,
                                                      float* __restrict__ fused) {
    __shared__ float ps[B_ * C_];
    __shared__ float hs[B_ * CR_];
    const int tid = threadIdx.x;
    for (int i = tid; i < B_ * C_; i += 256) ps[i] = pooled[i];
    __syncthreads();
    for (int v = tid; v < B_ * CR_; v += 256) {
        int b = v >> 6, r = v & 63;
        float acc = b1[r];
        const float* wr = w1 + (size_t)r * C_;
        const float* pb = ps + b * C_;
        for (int c = 0; c < C_; c += 4) {
            float4 wv = *(const float4*)(wr + c);
            acc += pb[c] * wv.x + pb[c + 1] * wv.y + pb[c + 2] * wv.z + pb[c + 3] * wv.w;
        }
        hs[v] = 0.5f * acc * (1.f + erff(acc * 0.70710678118654752f));
    }
    __syncthreads();

    int m = blockIdx.x * 256 + tid;   // < 12544
    float wrow[CR_];
    const float4* w4 = (const float4*)(w2 + (size_t)m * CR_);
#pragma unroll
    for (int i = 0; i < CR_ / 4; i++) {
        float4 v = w4[i];
        wrow[4 * i] = v.x; wrow[4 * i + 1] = v.y;
        wrow[4 * i + 2] = v.z; wrow[4 * i + 3] = v.w;
    }
    float base = b2[m] + dwt[m];
    for (int b = 0; b < B_; b++) {
        float acc = base;
        const float* hb = hs + b * CR_;
#pragma unroll
        for (int r = 0; r < CR_; r++) acc += hb[r] * wrow[r];
        fused[(size_t)b * (C_ * KK_) + m] = acc;
    }
}

// ---------------- K3: pack pw fp32 [o][c] -> Pa bf16 A-fragment-direct layout ----
// Pa[((kb*16 + ob)*4 + kq)*128 + oi*8 + (c&7)], kb=c>>5, kq=(c>>3)&3
// -> each wave A-fragment (16 o x 8 k) is 16 consecutive b128 lanes.
__global__ __launch_bounds__(256) void prep_kernel(const float* __restrict__ pw,
                                                   ushort* __restrict__ Pa) {
    int idx = blockIdx.x * 256 + threadIdx.x;   // 65536
    int o = idx >> 8, c = idx & 255;
    size_t e = (size_t)((((c >> 5) * 16 + (o >> 4)) * 4 + ((c >> 3) & 3)) * 128)
             + (o & 15) * 8 + (c & 7);
    Pa[e] = f2bf(pw[idx]);
}

// ---------------- K5: depthwise 7x7 (round-4 proven config) ----------------
// 8 ch x 16 rows/block, 512 thr, wave=channel, weights pinned in SGPRs,
// 4x4 micro-tile, manual vector staging. Ug: [b][p>>4][c>>3][p&15][c&7] bf16
__global__ __launch_bounds__(512, 4) void dw_kernel(const float* __restrict__ x,
                                                    const float* __restrict__ fused,
                                                    ushort* __restrict__ Ug) {
    __shared__ __align__(16) float xs[8 * 22 * 72];   // 50688 B; Us (16 KB) aliases later
    ushort* Us = (ushort*)xs;

    const int strip = blockIdx.x;            // 0..3
    const int cb    = blockIdx.y;            // 0..31
    const int b     = blockIdx.z;
    const int tid   = threadIdx.x;           // 0..511
    const int wid   = tid >> 6;              // wave-uniform channel
    const int lane  = tid & 63;
    const int c0    = cb * 8;
    const int r0    = strip * 16;

    // ---- stage x: wave wid loads channel wid; rows r0-3 .. r0+18 ----
    {
        const float* xp = x + (((size_t)(b * C_ + c0 + wid)) << 12);
        float* xd = xs + wid * 1584;
#pragma unroll
        for (int row = 0; row < 22; row++) {
            int gr = r0 + row - 3;           // wave-uniform -> scalar branch
            float v = 0.f;
            if ((unsigned)gr < 64u) v = xp[(gr << 6) + lane];
            xd[row * 72 + 3 + lane] = v;
        }
        for (int j = lane; j < 176; j += 64) {   // edge cols 0..2, 67..71
            int row = j >> 3, e = j & 7;
            int col = (e < 3) ? e : (64 + e);
            xd[row * 72 + col] = 0.f;
        }
    }

    // ---- weights -> SGPRs: one load + 49 readlanes, pinned ----
    float wk[49];
    {
        const float* fp = fused + (((size_t)b * C_) + c0 + wid) * KK_;
        float v = (lane < KK_) ? fp[lane] : 0.f;
        int vi = __float_as_int(v);
#pragma unroll
        for (int t = 0; t < 49; t++) {
            wk[t] = __int_as_float(__builtin_amdgcn_readlane(vi, t));
            asm volatile("" : "+s"(wk[t]));
        }
    }
    __syncthreads();

    const int cg = lane & 15;
    const int rg = lane >> 4;
    float acc[4][4];
#pragma unroll
    for (int ro = 0; ro < 4; ro++)
#pragma unroll
        for (int co = 0; co < 4; co++) acc[ro][co] = 0.f;

    const float* xbase = xs + wid * 1584 + (rg * 4) * 72 + cg * 4;
#pragma unroll
    for (int rr = 0; rr < 10; rr++) {
        float xr[10];
        *(float4*)&xr[0] = *(const float4*)(xbase + rr * 72);
        *(float4*)&xr[4] = *(const float4*)(xbase + rr * 72 + 4);
        *(float2*)&xr[8] = *(const float2*)(xbase + rr * 72 + 8);
        const int olo = (rr - 6 < 0) ? 0 : rr - 6;
        const int ohi = (rr < 3) ? rr : 3;
#pragma unroll
        for (int ro = olo; ro <= ohi; ro++) {
            const int ki = rr - ro;
#pragma unroll
            for (int j = 0; j < 7; j++) {
#pragma unroll
                for (int co = 0; co < 4; co++)
                    acc[ro][co] = fmaf(xr[co + j], wk[ki * 7 + j], acc[ro][co]);
            }
        }
    }
    __syncthreads();   // all xs reads done; safe to alias with Us

    // ---- stage bf16 outputs: chunk q = o*4 + c/16, slot = (c&15)*8 + ch ----
#pragma unroll
    for (int ro = 0; ro < 4; ro++) {
#pragma unroll
        for (int co = 0; co < 4; co++) {
            int o = rg * 4 + ro;
            int c = cg * 4 + co;
            Us[(o * 4 + (c >> 4)) * 128 + (c & 15) * 8 + wid] = f2bf(acc[ro][co]);
        }
    }
    __syncthreads();

    // ---- coalesced writeout: 64 chunks x 256B ----
    for (int t = tid; t < 1024; t += 512) {
        int q = t >> 4, part = t & 15;
        int o = q >> 2, cgrp = q & 3;
        size_t e = ((((size_t)b * 256) + (size_t)((r0 + o) * 4 + cgrp)) * 32 + cb) * 128
                   + (size_t)part * 8;
        *(uint4*)(Ug + e) = *(const uint4*)(Us + q * 128 + part * 8);
    }
}

// ---------------- K6: lean pointwise GEMM: A direct from L2, B ping-pong LDS ----------------
// Block: 256 thr (4 waves), tile 256o x 64px. Wave wid owns o = wid*64..+63.
// Per K-step (BK=32): each wave stages ONE 1KB B-chunk; single barrier; 16 MFMA.
__global__ __launch_bounds__(256, 4) void pw_kernel(const ushort* __restrict__ Pa,
                                                    const ushort* __restrict__ Ug,
                                                    float* __restrict__ Y) {
    __shared__ ushort Bs[2][2048];   // per buf: 64px x 32k = [pg(4)][kq(4)][16][8]
    const int pb   = blockIdx.x;     // 0..63  (64-px tiles)
    const int b    = blockIdx.y;
    const int tid  = threadIdx.x;
    const int wid  = tid >> 6;       // 0..3
    const int lane = tid & 63;
    const int oi   = lane & 15;
    const int kq   = lane >> 4;

    f32x4 acc[4][4];
#pragma unroll
    for (int mi = 0; mi < 4; mi++)
#pragma unroll
        for (int ni = 0; ni < 4; ni++)
            acc[mi][ni] = (f32x4){0.f, 0.f, 0.f, 0.f};

    const int p16 = pb * 4;          // first 16-px group

    // wave wid stages px-group (p16+wid) for K-step KB: 1KB contiguous in Ug
#define STAGEB(KB) GLDS16(Ug + ((((size_t)b * 256 + p16 + wid) * 32 + (KB) * 4) * 128) \
                              + lane * 8, &Bs[(KB) & 1][wid * 512])

    STAGEB(0);

#pragma unroll
    for (int kb = 0; kb < 8; kb++) {
        asm volatile("s_waitcnt vmcnt(0)" ::: "memory");   // own chunk for kb landed
        __builtin_amdgcn_s_barrier();                      // all chunks landed; prev buf free
        if (kb < 7) STAGEB(kb + 1);
        const int buf = kb & 1;

        short8 af[4], bf[4];
#pragma unroll
        for (int mi = 0; mi < 4; mi++) {
            const int ob = wid * 4 + mi;
            af[mi] = *(const short8*)(Pa + (size_t)(((kb * 16 + ob) * 4 + kq) * 128) + oi * 8);
        }
#pragma unroll
        for (int ni = 0; ni < 4; ni++)
            bf[ni] = *(const short8*)&Bs[buf][(ni * 4 + kq) * 128 + oi * 8];
#pragma unroll
        for (int mi = 0; mi < 4; mi++)
#pragma unroll
            for (int ni = 0; ni < 4; ni++)
                acc[mi][ni] = __builtin_amdgcn_mfma_f32_16x16x32_bf16(
                    bf[ni], af[mi], acc[mi][ni], 0, 0, 0);
    }

    // epilogue: D row = px (kq*4+r), D col = o (oi)  -> float4 stores along px
    float* yb = Y + ((size_t)b << 20);
    const int p0 = pb * 64;
#pragma unroll
    for (int mi = 0; mi < 4; mi++) {
        const int o = wid * 64 + mi * 16 + oi;
#pragma unroll
        for (int ni = 0; ni < 4; ni++) {
            const int p = p0 + ni * 16 + kq * 4;
            *(float4*)(yb + (size_t)o * HW_ + p) = *(float4*)&acc[mi][ni];
        }
    }
#undef STAGEB
}

extern "C" void kernel_launch(void* const* d_in, const int* in_sizes, int n_in,
                              void* d_out, int out_size, void* d_ws, size_t ws_size,
                              hipStream_t stream) {
    const float* x  = (const float*)d_in[0];
    const float* dw = (const float*)d_in[1];
    const float* pw = (const float*)d_in[2];
    const float* w1 = (const float*)d_in[3];
    const float* b1 = (const float*)d_in[4];
    const float* w2 = (const float*)d_in[5];
    const float* b2 = (const float*)d_in[6];
    float* out = (float*)d_out;

    char* ws = (char*)d_ws;
    float*  pooled = (float*)(ws);                    // 16384 B
    float*  fused  = (float*)(ws + 16384);            // 802816 B
    ushort* Pa     = (ushort*)(ws + 819200);          // 131072 B
    ushort* Ug     = (ushort*)(ws + 1048576);         // 33554432 B

    hipLaunchKernelGGL(pool_kernel,    dim3(B_ * C_), dim3(256), 0, stream, x, pooled);
    hipLaunchKernelGGL(mlpgenw_kernel, dim3(49), dim3(256), 0, stream,
                       pooled, w1, b1, w2, b2, dw, fused);
    hipLaunchKernelGGL(prep_kernel,    dim3(256), dim3(256), 0, stream, pw, Pa);
    hipLaunchKernelGGL(dw_kernel,      dim3(4, 32, B_), dim3(512), 0, stream, x, fused, Ug);
    hipLaunchKernelGGL(pw_kernel,      dim3(64, B_), dim3(256), 0, stream, Pa, Ug, out);
}